// Round 1
// baseline (324.786 us; speedup 1.0000x reference)
//
#include <hip/hip_runtime.h>
#include <stdint.h>

typedef unsigned int u32;
typedef unsigned long long u64;

#define BB 8
#define NN 8192
#define CC 80
#define KK 1000
#define NC (NN*CC)            // 655360
#define MAXIDX (NC-1)
#define NMS_THR 0.5f
#define SCORE_THR 0.05f
#define MAX_RATIO 4.135166556742356f
#define CLS_OFF 10000.0f
#define CAP 2048
#define NW 16                 // u64 words per mask row (ceil(1000/64))

// ---- workspace layout (bytes) ----
#define WS_HIST1   0
#define WS_HIST2   65536
#define WS_HIST3   131072
#define WS_PREFIX  196608
#define WS_KNEED   196672
#define WS_SSTAR   196736
#define WS_GCOUNT  196800
#define WS_CTRL_END 197632     // memset range [0, WS_CTRL_END)
#define WS_GBUF    200704      // B*CAP*8 = 131072
#define WS_TBOX    331776      // B*K*4*4 = 128000
#define WS_TOBOX   459776      // 128000
#define WS_TSCORE  587776      // 32000
#define WS_TCLS    619776      // 32000
#define WS_TVALID  651776      // 32000
#define WS_MASK    683776      // B*K*NW*8 = 1024000 -> ends 1707776

__device__ __forceinline__ u32 mapf(float f) {
    u32 u = __float_as_uint(f);
    return (u & 0x80000000u) ? ~u : (u | 0x80000000u);
}
__device__ __forceinline__ float unmapf(u32 m) {
    u32 u = (m & 0x80000000u) ? (m ^ 0x80000000u) : ~m;
    return __uint_as_float(u);
}

// ---------------- histogram pass (radix select) ----------------
__global__ void hist_pass(const float* __restrict__ scores, u32* __restrict__ hist,
                          const u32* __restrict__ prefix, int pass) {
    __shared__ u32 lh[2048];
    int b = blockIdx.y;
    for (int i = threadIdx.x; i < 2048; i += blockDim.x) lh[i] = 0;
    __syncthreads();
    u32 pfx = (pass == 0) ? 0u : prefix[b];
    const float4* sp = (const float4*)(scores + (size_t)b * NC);
    int nvec = NC / 4;
    for (int v = blockIdx.x * blockDim.x + threadIdx.x; v < nvec; v += gridDim.x * blockDim.x) {
        float4 s4 = sp[v];
        float ss[4] = {s4.x, s4.y, s4.z, s4.w};
        #pragma unroll
        for (int q = 0; q < 4; ++q) {
            float s = ss[q] > SCORE_THR ? ss[q] : -1.0f;
            u32 m = mapf(s);
            if (pass == 0) {
                atomicAdd(&lh[m >> 21], 1u);
            } else if (pass == 1) {
                if ((m >> 21) == pfx) atomicAdd(&lh[(m >> 10) & 0x7FFu], 1u);
            } else {
                if ((m >> 10) == pfx) atomicAdd(&lh[m & 0x3FFu], 1u);
            }
        }
    }
    __syncthreads();
    for (int i = threadIdx.x; i < 2048; i += blockDim.x)
        if (lh[i]) atomicAdd(&hist[b * 2048 + i], lh[i]);
}

// ---------------- select digit ----------------
__global__ void select_pass(const u32* __restrict__ hist, u32* prefix,
                            u32* kneed, u32* sstar, int pass) {
    __shared__ u32 csum[256];
    int b = blockIdx.x;
    const u32* h = hist + b * 2048;
    int t = threadIdx.x;
    u32 s = 0;
    #pragma unroll
    for (int q = 0; q < 8; ++q) s += h[t * 8 + q];
    csum[t] = s;
    __syncthreads();
    if (t == 0) {
        u32 need = (pass == 0) ? (u32)KK : kneed[b];
        u32 cum = 0;
        int d = 0;
        for (int c = 255; c >= 0; --c) {
            if (cum + csum[c] >= need) {
                for (int q = 7; q >= 0; --q) {
                    u32 hc = h[c * 8 + q];
                    if (cum + hc >= need) { d = c * 8 + q; break; }
                    cum += hc;
                }
                break;
            }
            cum += csum[c];
        }
        if (pass == 0)      { prefix[b] = (u32)d;                       kneed[b] = need - cum; }
        else if (pass == 1) { prefix[b] = (prefix[b] << 11) | (u32)d;   kneed[b] = need - cum; }
        else                { sstar[b]  = (prefix[b] << 10) | (u32)d; }
    }
}

// ---------------- gather all >= s* ----------------
__global__ void gather_pass(const float* __restrict__ scores, const u32* __restrict__ sstar,
                            u64* __restrict__ gbuf, u32* __restrict__ gcount) {
    int b = blockIdx.y;
    u32 thr = sstar[b];
    const float4* sp = (const float4*)(scores + (size_t)b * NC);
    int nvec = NC / 4;
    for (int v = blockIdx.x * blockDim.x + threadIdx.x; v < nvec; v += gridDim.x * blockDim.x) {
        float4 s4 = sp[v];
        float ss[4] = {s4.x, s4.y, s4.z, s4.w};
        #pragma unroll
        for (int q = 0; q < 4; ++q) {
            float s = ss[q] > SCORE_THR ? ss[q] : -1.0f;
            u32 m = mapf(s);
            if (m >= thr) {
                u32 pos = atomicAdd(&gcount[b], 1u);
                if (pos < CAP) {
                    u32 idx = (u32)(v * 4 + q);
                    gbuf[(size_t)b * CAP + pos] = ((u64)m << 32) | (u64)(MAXIDX - idx);
                }
            }
        }
    }
}

// ---------------- sort (bitonic, desc) + decode top-K ----------------
__global__ __launch_bounds__(1024) void sort_decode(
    const u64* __restrict__ gbuf, const u32* __restrict__ gcount,
    const float* __restrict__ rois, const float* __restrict__ reg,
    float* __restrict__ tbox, float* __restrict__ tobox,
    float* __restrict__ tscore, float* __restrict__ tcls, u32* __restrict__ tvalid) {
    __shared__ u64 keys[CAP];
    int b = blockIdx.x;
    u32 cnt = gcount[b]; if (cnt > CAP) cnt = CAP;
    for (int i = threadIdx.x; i < CAP; i += blockDim.x)
        keys[i] = (i < (int)cnt) ? gbuf[(size_t)b * CAP + i] : 0ull;
    __syncthreads();
    for (int k = 2; k <= CAP; k <<= 1) {
        for (int j = k >> 1; j > 0; j >>= 1) {
            for (int i = threadIdx.x; i < CAP; i += blockDim.x) {
                int ixj = i ^ j;
                if (ixj > i) {
                    u64 a = keys[i], c = keys[ixj];
                    bool desc = ((i & k) == 0);
                    if ((a < c) == desc) { keys[i] = c; keys[ixj] = a; }
                }
            }
            __syncthreads();
        }
    }
    for (int kk = threadIdx.x; kk < KK; kk += blockDim.x) {
        u64 key = keys[kk];
        float score, cf, box0, box1, box2, box3;
        u32 vld;
        if (kk < (int)cnt) {
            u32 m = (u32)(key >> 32);
            u32 idx = (u32)MAXIDX - (u32)(key & 0xFFFFFFFFu);
            score = unmapf(m);
            vld = (score > SCORE_THR) ? 1u : 0u;
            int n = idx / CC, c = idx % CC;
            cf = (float)(c + 1);
            const float* r = rois + ((size_t)b * NN + n) * 4;
            const float* d = reg  + ((size_t)b * NN + n) * 4;
            float x1 = r[0], y1 = r[1], x2 = r[2], y2 = r[3];
            float w = x2 - x1, h = y2 - y1;
            float cx = x1 + 0.5f * w, cy = y1 + 0.5f * h;
            float dx = d[0], dy = d[1];
            float dw = fminf(fmaxf(d[2], -MAX_RATIO), MAX_RATIO);
            float dh = fminf(fmaxf(d[3], -MAX_RATIO), MAX_RATIO);
            float pw = w * expf(dw), ph = h * expf(dh);
            float pcx = cx + dx * w, pcy = cy + dy * h;
            box0 = pcx - 0.5f * pw; box1 = pcy - 0.5f * ph;
            box2 = pcx + 0.5f * pw; box3 = pcy + 0.5f * ph;
        } else {
            score = -1.0f; cf = 0.0f; vld = 0u; box0 = box1 = box2 = box3 = 0.0f;
        }
        size_t o = (size_t)b * KK + kk;
        tscore[o] = score; tcls[o] = cf; tvalid[o] = vld;
        float off = cf * CLS_OFF;
        tbox[o*4+0] = box0; tbox[o*4+1] = box1; tbox[o*4+2] = box2; tbox[o*4+3] = box3;
        tobox[o*4+0] = box0 + off; tobox[o*4+1] = box1 + off;
        tobox[o*4+2] = box2 + off; tobox[o*4+3] = box3 + off;
    }
}

// ---------------- IoU > thr bitmask ----------------
__global__ void iou_mask(const float* __restrict__ obox, u64* __restrict__ mask) {
    __shared__ float jb[64][4];
    int b = blockIdx.z, ib = blockIdx.x, jbk = blockIdx.y;
    int t = threadIdx.x;
    int j0 = jbk * 64;
    int jg = j0 + t;
    if (jg < KK) {
        const float* p = obox + ((size_t)b * KK + jg) * 4;
        jb[t][0] = p[0]; jb[t][1] = p[1]; jb[t][2] = p[2]; jb[t][3] = p[3];
    } else {
        jb[t][0] = 0; jb[t][1] = 0; jb[t][2] = 0; jb[t][3] = 0;
    }
    __syncthreads();
    int i = ib * 64 + t;
    if (i >= KK) return;
    const float* p = obox + ((size_t)b * KK + i) * 4;
    float x1 = p[0], y1 = p[1], x2 = p[2], y2 = p[3];
    float ai = (x2 - x1) * (y2 - y1);
    u64 bits = 0;
    int jmax = min(64, KK - j0);
    for (int jj = 0; jj < jmax; ++jj) {
        float bx1 = jb[jj][0], by1 = jb[jj][1], bx2 = jb[jj][2], by2 = jb[jj][3];
        float aj = (bx2 - bx1) * (by2 - by1);
        float iw = fmaxf(fminf(x2, bx2) - fmaxf(x1, bx1), 0.0f);
        float ih = fmaxf(fminf(y2, by2) - fmaxf(y1, by1), 0.0f);
        float inter = iw * ih;
        float iou = inter / (ai + aj - inter + 1e-9f);
        if (iou > NMS_THR) bits |= (1ull << jj);
    }
    mask[((size_t)b * KK + i) * NW + jbk] = bits;
}

// ---------------- serial greedy NMS scan + output ----------------
__global__ __launch_bounds__(256) void nms_scan(
    const u64* __restrict__ mask, const u32* __restrict__ tvalid,
    const float* __restrict__ tbox, const float* __restrict__ tscore,
    const float* __restrict__ tcls, float* __restrict__ out) {
    __shared__ u32 svalid[KK];
    __shared__ float skeep[KK];
    int b = blockIdx.x;
    for (int i = threadIdx.x; i < KK; i += blockDim.x) svalid[i] = tvalid[(size_t)b * KK + i];
    __syncthreads();
    if (threadIdx.x < 64) {
        int lane = threadIdx.x;
        const u64* mrow = mask + (size_t)b * KK * NW;
        u64 remv = 0;
        #define LD(i) ((lane < NW && (i) < KK) ? mrow[(size_t)(i) * NW + lane] : 0ull)
        u64 r0 = LD(0), r1 = LD(1), r2 = LD(2), r3 = LD(3);
        u64 r4 = LD(4), r5 = LD(5), r6 = LD(6), r7 = LD(7);
        for (int i = 0; i < KK; i += 8) {
            #define STEP(RR, OFF) { \
                int ii = i + OFF; \
                u64 w = __shfl(remv, ii >> 6, 64); \
                bool keep = (svalid[ii] != 0) && !((w >> (ii & 63)) & 1ull); \
                if (keep) remv |= RR; \
                if (lane == 0) skeep[ii] = keep ? 1.0f : 0.0f; \
                RR = LD(ii + 8); \
            }
            STEP(r0, 0) STEP(r1, 1) STEP(r2, 2) STEP(r3, 3)
            STEP(r4, 4) STEP(r5, 5) STEP(r6, 6) STEP(r7, 7)
            #undef STEP
        }
        #undef LD
    }
    __syncthreads();
    for (int kk = threadIdx.x; kk < KK; kk += blockDim.x) {
        size_t o = (size_t)b * KK + kk;
        float kf = skeep[kk];
        float* op = out + o * 7;
        op[0] = tbox[o*4+0] * kf; op[1] = tbox[o*4+1] * kf;
        op[2] = tbox[o*4+2] * kf; op[3] = tbox[o*4+3] * kf;
        op[4] = tscore[o] * kf;   op[5] = tcls[o] * kf;   op[6] = kf;
    }
}

extern "C" void kernel_launch(void* const* d_in, const int* in_sizes, int n_in,
                              void* d_out, int out_size, void* d_ws, size_t ws_size,
                              hipStream_t stream) {
    const float* rois   = (const float*)d_in[0];   // (B,N,4)
    const float* scores = (const float*)d_in[1];   // (B*N,C,1,1) == (B, N*C)
    const float* reg    = (const float*)d_in[2];   // (B*N,4,1,1)
    float* out = (float*)d_out;

    char* ws = (char*)d_ws;
    u32* hist1  = (u32*)(ws + WS_HIST1);
    u32* hist2  = (u32*)(ws + WS_HIST2);
    u32* hist3  = (u32*)(ws + WS_HIST3);
    u32* prefix = (u32*)(ws + WS_PREFIX);
    u32* kneed  = (u32*)(ws + WS_KNEED);
    u32* sstar  = (u32*)(ws + WS_SSTAR);
    u32* gcount = (u32*)(ws + WS_GCOUNT);
    u64* gbuf   = (u64*)(ws + WS_GBUF);
    float* tbox   = (float*)(ws + WS_TBOX);
    float* tobox  = (float*)(ws + WS_TOBOX);
    float* tscore = (float*)(ws + WS_TSCORE);
    float* tcls   = (float*)(ws + WS_TCLS);
    u32*   tvalid = (u32*)(ws + WS_TVALID);
    u64*   mask   = (u64*)(ws + WS_MASK);

    hipMemsetAsync(d_ws, 0, WS_CTRL_END, stream);

    dim3 hgrid(64, BB);
    hist_pass<<<hgrid, 256, 0, stream>>>(scores, hist1, prefix, 0);
    select_pass<<<BB, 256, 0, stream>>>(hist1, prefix, kneed, sstar, 0);
    hist_pass<<<hgrid, 256, 0, stream>>>(scores, hist2, prefix, 1);
    select_pass<<<BB, 256, 0, stream>>>(hist2, prefix, kneed, sstar, 1);
    hist_pass<<<hgrid, 256, 0, stream>>>(scores, hist3, prefix, 2);
    select_pass<<<BB, 256, 0, stream>>>(hist3, prefix, kneed, sstar, 2);

    gather_pass<<<hgrid, 256, 0, stream>>>(scores, sstar, gbuf, gcount);

    sort_decode<<<BB, 1024, 0, stream>>>(gbuf, gcount, rois, reg,
                                         tbox, tobox, tscore, tcls, tvalid);

    iou_mask<<<dim3(16, 16, BB), 64, 0, stream>>>(tobox, mask);

    nms_scan<<<BB, 256, 0, stream>>>(mask, tvalid, tbox, tscore, tcls, out);
}

// Round 2
// 179.959 us; speedup vs baseline: 1.8048x; 1.8048x over previous
//
#include <hip/hip_runtime.h>
#include <stdint.h>

typedef unsigned int u32;
typedef unsigned long long u64;

#define BB 8
#define NN 8192
#define CC 80
#define KK 1000
#define NC (NN*CC)            // 655360
#define MAXIDX (NC-1)
#define NMS_THR 0.5f
#define SCORE_THR 0.05f
#define MAX_RATIO 4.135166556742356f
#define CLS_OFF 10000.0f
#define CAP 2048
#define NW 16                 // u64 words per mask row (ceil(1000/64))

// ---- workspace layout (bytes) ----
#define WS_HIST1   0          // 8*2048*4 = 65536
#define WS_HIST2   65536      // 65536
#define WS_PREFIX  131072     // 32
#define WS_KNEED   131136
#define WS_SSTAR   131200
#define WS_GCOUNT  131264
#define WS_CTRL_END 131328    // memset range [0, WS_CTRL_END)
#define WS_GBUF    131584     // B*CAP*8 = 131072 -> ends 262656
#define WS_TBOX    262656     // B*K*4*4 = 128000
#define WS_TOBOX   390656     // 128000
#define WS_TSCORE  518656     // 32000
#define WS_TCLS    550656     // 32000
#define WS_TVALID  582656     // 32000
#define WS_MASK    614656     // transposed: B*NW*KK*8 = 1024000 -> ends 1638656

__device__ __forceinline__ u32 mapf(float f) {
    u32 u = __float_as_uint(f);
    return (u & 0x80000000u) ? ~u : (u | 0x80000000u);
}
__device__ __forceinline__ float unmapf(u32 m) {
    u32 u = (m & 0x80000000u) ? (m ^ 0x80000000u) : ~m;
    return __uint_as_float(u);
}

// ---------------- histogram pass (radix select, 2 passes of 11 bits) ----------------
__global__ void hist_pass(const float* __restrict__ scores, u32* __restrict__ hist,
                          const u32* __restrict__ prefix, int pass) {
    __shared__ u32 lh[2048];
    int b = blockIdx.y;
    for (int i = threadIdx.x; i < 2048; i += blockDim.x) lh[i] = 0;
    __syncthreads();
    u32 pfx = (pass == 0) ? 0u : prefix[b];
    const float4* sp = (const float4*)(scores + (size_t)b * NC);
    int nvec = NC / 4;
    for (int v = blockIdx.x * blockDim.x + threadIdx.x; v < nvec; v += gridDim.x * blockDim.x) {
        float4 s4 = sp[v];
        float ss[4] = {s4.x, s4.y, s4.z, s4.w};
        #pragma unroll
        for (int q = 0; q < 4; ++q) {
            float s = ss[q] > SCORE_THR ? ss[q] : -1.0f;
            u32 m = mapf(s);
            if (pass == 0) {
                atomicAdd(&lh[m >> 21], 1u);
            } else {
                if ((m >> 21) == pfx) atomicAdd(&lh[(m >> 10) & 0x7FFu], 1u);
            }
        }
    }
    __syncthreads();
    for (int i = threadIdx.x; i < 2048; i += blockDim.x)
        if (lh[i]) atomicAdd(&hist[b * 2048 + i], lh[i]);
}

// ---------------- select digit ----------------
__global__ void select_pass(const u32* __restrict__ hist, u32* prefix,
                            u32* kneed, u32* sstar, int pass) {
    __shared__ u32 csum[256];
    int b = blockIdx.x;
    const u32* h = hist + b * 2048;
    int t = threadIdx.x;
    u32 s = 0;
    #pragma unroll
    for (int q = 0; q < 8; ++q) s += h[t * 8 + q];
    csum[t] = s;
    __syncthreads();
    if (t == 0) {
        u32 need = (pass == 0) ? (u32)KK : kneed[b];
        u32 cum = 0;
        int d = 0;
        for (int c = 255; c >= 0; --c) {
            if (cum + csum[c] >= need) {
                for (int q = 7; q >= 0; --q) {
                    u32 hc = h[c * 8 + q];
                    if (cum + hc >= need) { d = c * 8 + q; break; }
                    cum += hc;
                }
                break;
            }
            cum += csum[c];
        }
        if (pass == 0) { prefix[b] = (u32)d; kneed[b] = need - cum; }
        else           { sstar[b]  = ((prefix[b] << 11) | (u32)d) << 10; }
    }
}

// ---------------- gather all >= s* (22-bit prefix threshold) ----------------
__global__ void gather_pass(const float* __restrict__ scores, const u32* __restrict__ sstar,
                            u64* __restrict__ gbuf, u32* __restrict__ gcount) {
    int b = blockIdx.y;
    u32 thr = sstar[b];
    const float4* sp = (const float4*)(scores + (size_t)b * NC);
    int nvec = NC / 4;
    for (int v = blockIdx.x * blockDim.x + threadIdx.x; v < nvec; v += gridDim.x * blockDim.x) {
        float4 s4 = sp[v];
        float ss[4] = {s4.x, s4.y, s4.z, s4.w};
        #pragma unroll
        for (int q = 0; q < 4; ++q) {
            float s = ss[q] > SCORE_THR ? ss[q] : -1.0f;
            u32 m = mapf(s);
            if (m >= thr) {
                u32 pos = atomicAdd(&gcount[b], 1u);
                if (pos < CAP) {
                    u32 idx = (u32)(v * 4 + q);
                    gbuf[(size_t)b * CAP + pos] = ((u64)m << 32) | (u64)(MAXIDX - idx);
                }
            }
        }
    }
}

// ---------------- sort (bitonic, desc) + decode top-K ----------------
__global__ __launch_bounds__(1024) void sort_decode(
    const u64* __restrict__ gbuf, const u32* __restrict__ gcount,
    const float* __restrict__ rois, const float* __restrict__ reg,
    float* __restrict__ tbox, float* __restrict__ tobox,
    float* __restrict__ tscore, float* __restrict__ tcls, u32* __restrict__ tvalid) {
    __shared__ u64 keys[CAP];
    int b = blockIdx.x;
    u32 cnt = gcount[b]; if (cnt > CAP) cnt = CAP;
    for (int i = threadIdx.x; i < CAP; i += blockDim.x)
        keys[i] = (i < (int)cnt) ? gbuf[(size_t)b * CAP + i] : 0ull;
    __syncthreads();
    for (int k = 2; k <= CAP; k <<= 1) {
        for (int j = k >> 1; j > 0; j >>= 1) {
            for (int i = threadIdx.x; i < CAP; i += blockDim.x) {
                int ixj = i ^ j;
                if (ixj > i) {
                    u64 a = keys[i], c = keys[ixj];
                    bool desc = ((i & k) == 0);
                    if ((a < c) == desc) { keys[i] = c; keys[ixj] = a; }
                }
            }
            __syncthreads();
        }
    }
    for (int kk = threadIdx.x; kk < KK; kk += blockDim.x) {
        u64 key = keys[kk];
        float score, cf, box0, box1, box2, box3;
        u32 vld;
        if (kk < (int)cnt) {
            u32 m = (u32)(key >> 32);
            u32 idx = (u32)MAXIDX - (u32)(key & 0xFFFFFFFFu);
            score = unmapf(m);
            vld = (score > SCORE_THR) ? 1u : 0u;
            int n = idx / CC, c = idx % CC;
            cf = (float)(c + 1);
            const float* r = rois + ((size_t)b * NN + n) * 4;
            const float* d = reg  + ((size_t)b * NN + n) * 4;
            float x1 = r[0], y1 = r[1], x2 = r[2], y2 = r[3];
            float w = x2 - x1, h = y2 - y1;
            float cx = x1 + 0.5f * w, cy = y1 + 0.5f * h;
            float dx = d[0], dy = d[1];
            float dw = fminf(fmaxf(d[2], -MAX_RATIO), MAX_RATIO);
            float dh = fminf(fmaxf(d[3], -MAX_RATIO), MAX_RATIO);
            float pw = w * expf(dw), ph = h * expf(dh);
            float pcx = cx + dx * w, pcy = cy + dy * h;
            box0 = pcx - 0.5f * pw; box1 = pcy - 0.5f * ph;
            box2 = pcx + 0.5f * pw; box3 = pcy + 0.5f * ph;
        } else {
            score = -1.0f; cf = 0.0f; vld = 0u; box0 = box1 = box2 = box3 = 0.0f;
        }
        size_t o = (size_t)b * KK + kk;
        tscore[o] = score; tcls[o] = cf; tvalid[o] = vld;
        float off = cf * CLS_OFF;
        tbox[o*4+0] = box0; tbox[o*4+1] = box1; tbox[o*4+2] = box2; tbox[o*4+3] = box3;
        tobox[o*4+0] = box0 + off; tobox[o*4+1] = box1 + off;
        tobox[o*4+2] = box2 + off; tobox[o*4+3] = box3 + off;
    }
}

// ---------------- IoU > thr bitmask, TRANSPOSED layout: maskT[b][w][i] ----------------
__global__ void iou_mask(const float* __restrict__ obox, u64* __restrict__ maskT) {
    __shared__ float jb[64][4];
    int b = blockIdx.z, ib = blockIdx.x, jbk = blockIdx.y;
    int t = threadIdx.x;
    int j0 = jbk * 64;
    int jg = j0 + t;
    if (jg < KK) {
        const float* p = obox + ((size_t)b * KK + jg) * 4;
        jb[t][0] = p[0]; jb[t][1] = p[1]; jb[t][2] = p[2]; jb[t][3] = p[3];
    } else {
        jb[t][0] = 0; jb[t][1] = 0; jb[t][2] = 0; jb[t][3] = 0;
    }
    __syncthreads();
    int i = ib * 64 + t;
    if (i >= KK) return;
    const float* p = obox + ((size_t)b * KK + i) * 4;
    float x1 = p[0], y1 = p[1], x2 = p[2], y2 = p[3];
    float ai = (x2 - x1) * (y2 - y1);
    u64 bits = 0;
    int jmax = min(64, KK - j0);
    for (int jj = 0; jj < jmax; ++jj) {
        float bx1 = jb[jj][0], by1 = jb[jj][1], bx2 = jb[jj][2], by2 = jb[jj][3];
        float aj = (bx2 - bx1) * (by2 - by1);
        float iw = fmaxf(fminf(x2, bx2) - fmaxf(x1, bx1), 0.0f);
        float ih = fmaxf(fminf(y2, by2) - fmaxf(y1, by1), 0.0f);
        float inter = iw * ih;
        float iou = inter / (ai + aj - inter + 1e-9f);
        if (iou > NMS_THR) bits |= (1ull << jj);
    }
    // transposed: word-block major, item minor -> coalesced for the scan
    maskT[((size_t)b * NW + jbk) * KK + i] = bits;
}

// ---------------- blocked ballot fixed-point NMS + output ----------------
__global__ __launch_bounds__(256) void nms_scan(
    const u64* __restrict__ maskT, const u32* __restrict__ tvalid,
    const float* __restrict__ tbox, const float* __restrict__ tscore,
    const float* __restrict__ tcls, float* __restrict__ out) {
    __shared__ u64 skept[NW];
    int b = blockIdx.x;
    if (threadIdx.x < 64) {
        int lane = threadIdx.x;
        const u64* mT = maskT + (size_t)b * NW * KK;
        u64 keptW[NW];
        #pragma unroll
        for (int W = 0; W < NW; ++W) {
            int i = W * 64 + lane;
            bool inr = (i < KK);
            u64 row[NW];
            #pragma unroll
            for (int w = 0; w <= W; ++w)
                row[w] = inr ? mT[(size_t)w * KK + i] : 0ull;
            bool valid = inr && (tvalid[(size_t)b * KK + i] != 0u);
            u64 ext = 0;
            #pragma unroll
            for (int w = 0; w < W; ++w) ext |= keptW[w] & row[w];
            bool cand = valid && (ext == 0ull);
            u64 m_self = row[W] & ((1ull << lane) - 1ull);   // strictly-lower lanes
            u64 kept = __ballot(cand);
            while (true) {
                u64 k2 = __ballot(cand && ((kept & m_self) == 0ull));
                if (k2 == kept) break;
                kept = k2;
            }
            keptW[W] = kept;
            if (lane == 0) skept[W] = kept;
        }
    }
    __syncthreads();
    for (int kk = threadIdx.x; kk < KK; kk += blockDim.x) {
        size_t o = (size_t)b * KK + kk;
        float kf = (float)((skept[kk >> 6] >> (kk & 63)) & 1ull);
        float* op = out + o * 7;
        op[0] = tbox[o*4+0] * kf; op[1] = tbox[o*4+1] * kf;
        op[2] = tbox[o*4+2] * kf; op[3] = tbox[o*4+3] * kf;
        op[4] = tscore[o] * kf;   op[5] = tcls[o] * kf;   op[6] = kf;
    }
}

extern "C" void kernel_launch(void* const* d_in, const int* in_sizes, int n_in,
                              void* d_out, int out_size, void* d_ws, size_t ws_size,
                              hipStream_t stream) {
    const float* rois   = (const float*)d_in[0];   // (B,N,4)
    const float* scores = (const float*)d_in[1];   // (B*N,C,1,1) == (B, N*C)
    const float* reg    = (const float*)d_in[2];   // (B*N,4,1,1)
    float* out = (float*)d_out;

    char* ws = (char*)d_ws;
    u32* hist1  = (u32*)(ws + WS_HIST1);
    u32* hist2  = (u32*)(ws + WS_HIST2);
    u32* prefix = (u32*)(ws + WS_PREFIX);
    u32* kneed  = (u32*)(ws + WS_KNEED);
    u32* sstar  = (u32*)(ws + WS_SSTAR);
    u32* gcount = (u32*)(ws + WS_GCOUNT);
    u64* gbuf   = (u64*)(ws + WS_GBUF);
    float* tbox   = (float*)(ws + WS_TBOX);
    float* tobox  = (float*)(ws + WS_TOBOX);
    float* tscore = (float*)(ws + WS_TSCORE);
    float* tcls   = (float*)(ws + WS_TCLS);
    u32*   tvalid = (u32*)(ws + WS_TVALID);
    u64*   maskT  = (u64*)(ws + WS_MASK);

    hipMemsetAsync(d_ws, 0, WS_CTRL_END, stream);

    dim3 hgrid(64, BB);
    hist_pass<<<hgrid, 256, 0, stream>>>(scores, hist1, prefix, 0);
    select_pass<<<BB, 256, 0, stream>>>(hist1, prefix, kneed, sstar, 0);
    hist_pass<<<hgrid, 256, 0, stream>>>(scores, hist2, prefix, 1);
    select_pass<<<BB, 256, 0, stream>>>(hist2, prefix, kneed, sstar, 1);

    gather_pass<<<hgrid, 256, 0, stream>>>(scores, sstar, gbuf, gcount);

    sort_decode<<<BB, 1024, 0, stream>>>(gbuf, gcount, rois, reg,
                                         tbox, tobox, tscore, tcls, tvalid);

    iou_mask<<<dim3(16, 16, BB), 64, 0, stream>>>(tobox, maskT);

    nms_scan<<<BB, 256, 0, stream>>>(maskT, tvalid, tbox, tscore, tcls, out);
}

// Round 3
// 143.037 us; speedup vs baseline: 2.2706x; 1.2581x over previous
//
#include <hip/hip_runtime.h>
#include <stdint.h>

typedef unsigned int u32;
typedef unsigned long long u64;

#define BB 8
#define NN 8192
#define CC 80
#define KK 1000
#define NC (NN*CC)            // 655360
#define MAXIDX (NC-1)
#define NMS_THR 0.5f
#define SCORE_THR 0.05f
#define MAX_RATIO 4.135166556742356f
#define CLS_OFF 10000.0f
#define CAP 2048
#define NW 16                 // u64 words per mask row (ceil(1000/64))
#define SCAN_BLOCKS 128       // blocks per batch for scan kernels

// ---- workspace layout (bytes) ----
#define WS_HIST1   0          // 8*2048*4 = 65536
#define WS_HIST2   65536      // 65536
#define WS_PREFIX  131072     // 32
#define WS_KNEED   131136
#define WS_SSTAR   131200
#define WS_GCOUNT  131264
#define WS_CTRL_END 131328    // memset range [0, WS_CTRL_END)
#define WS_GBUF    131584     // B*CAP*8 = 131072 -> ends 262656
#define WS_TBOX    262656     // B*K*4*4 = 128000
#define WS_TOBOX   390656     // 128000
#define WS_TSCORE  518656     // 32000
#define WS_TCLS    550656     // 32000
#define WS_TVALID  582656     // 32000
#define WS_MASK    614656     // transposed: B*NW*KK*8 = 1024000 -> ends 1638656

__device__ __forceinline__ u32 mapf(float f) {
    u32 u = __float_as_uint(f);
    return (u & 0x80000000u) ? ~u : (u | 0x80000000u);
}
__device__ __forceinline__ float unmapf(u32 m) {
    u32 u = (m & 0x80000000u) ? (m ^ 0x80000000u) : ~m;
    return __uint_as_float(u);
}

// wave-aggregated LDS histogram add: one atomic per distinct bin per wave
__device__ __forceinline__ void agg_lds_add(u32* lh, u32 bin, bool active) {
    u64 unproc = __ballot(active);
    const int lane = threadIdx.x & 63;
    while (unproc) {
        int leader = __ffsll(unproc) - 1;
        u32 lbin = (u32)__shfl((int)bin, leader, 64);
        u64 match = __ballot(active && (bin == lbin));
        if (lane == leader) atomicAdd(&lh[lbin], (u32)__popcll(match));
        unproc &= ~match;
    }
}

// ---------------- histogram pass (radix select, 2 passes of 11 bits) ----------------
__global__ __launch_bounds__(256) void hist_pass(
    const float* __restrict__ scores, u32* __restrict__ hist,
    const u32* __restrict__ prefix, int pass) {
    __shared__ u32 lh[2048];
    int b = blockIdx.y;
    for (int i = threadIdx.x; i < 2048; i += blockDim.x) lh[i] = 0;
    __syncthreads();
    u32 pfx = (pass == 0) ? 0u : prefix[b];
    const float4* sp = (const float4*)(scores + (size_t)b * NC);
    int nvec = NC / 4;
    for (int v = blockIdx.x * blockDim.x + threadIdx.x; v < nvec; v += gridDim.x * blockDim.x) {
        float4 s4 = sp[v];
        float ss[4] = {s4.x, s4.y, s4.z, s4.w};
        #pragma unroll
        for (int q = 0; q < 4; ++q) {
            float s = ss[q] > SCORE_THR ? ss[q] : -1.0f;
            u32 m = mapf(s);
            if (pass == 0) {
                agg_lds_add(lh, m >> 21, true);
            } else {
                agg_lds_add(lh, (m >> 10) & 0x7FFu, (m >> 21) == pfx);
            }
        }
    }
    __syncthreads();
    for (int i = threadIdx.x; i < 2048; i += blockDim.x)
        if (lh[i]) atomicAdd(&hist[b * 2048 + i], lh[i]);
}

// ---------------- select digit (parallel suffix-scan) ----------------
__global__ __launch_bounds__(256) void select_pass(
    const u32* __restrict__ hist, u32* prefix, u32* kneed, u32* sstar, int pass) {
    __shared__ u32 suf[256];
    int b = blockIdx.x;
    const u32* h = hist + b * 2048;
    int t = threadIdx.x;
    u32 hv[8];
    u32 s = 0;
    #pragma unroll
    for (int q = 0; q < 8; ++q) { hv[q] = h[t * 8 + q]; s += hv[q]; }
    u32 grp = s;
    suf[t] = s;
    __syncthreads();
    #pragma unroll
    for (int off = 1; off < 256; off <<= 1) {
        u32 v = (t + off < 256) ? suf[t + off] : 0u;
        __syncthreads();
        suf[t] += v;
        __syncthreads();
    }
    u32 need = (pass == 0) ? (u32)KK : kneed[b];
    u32 cumAbove = suf[t] - grp;
    if (cumAbove < need && suf[t] >= need) {   // unique boundary group
        u32 cum = cumAbove;
        int d = t * 8;
        for (int q = 7; q >= 0; --q) {
            if (cum + hv[q] >= need) { d = t * 8 + q; break; }
            cum += hv[q];
        }
        if (pass == 0) { prefix[b] = (u32)d; kneed[b] = need - cum; }
        else           { sstar[b]  = ((prefix[b] << 11) | (u32)d) << 10; }
    }
}

// ---------------- gather all >= s* (block-aggregated compaction) ----------------
__global__ __launch_bounds__(256) void gather_pass(
    const float* __restrict__ scores, const u32* __restrict__ sstar,
    u64* __restrict__ gbuf, u32* __restrict__ gcount) {
    __shared__ u64 buf[CAP];
    __shared__ u32 lcnt, lbase;
    int b = blockIdx.y;
    if (threadIdx.x == 0) lcnt = 0;
    __syncthreads();
    u32 thr = sstar[b];
    const float4* sp = (const float4*)(scores + (size_t)b * NC);
    int nvec = NC / 4;
    for (int v = blockIdx.x * blockDim.x + threadIdx.x; v < nvec; v += gridDim.x * blockDim.x) {
        float4 s4 = sp[v];
        float ss[4] = {s4.x, s4.y, s4.z, s4.w};
        #pragma unroll
        for (int q = 0; q < 4; ++q) {
            float s = ss[q] > SCORE_THR ? ss[q] : -1.0f;
            u32 m = mapf(s);
            if (m >= thr) {
                u32 pos = atomicAdd(&lcnt, 1u);
                if (pos < CAP) {
                    u32 idx = (u32)(v * 4 + q);
                    buf[pos] = ((u64)m << 32) | (u64)(MAXIDX - idx);
                }
            }
        }
    }
    __syncthreads();
    if (threadIdx.x == 0) {
        u32 c = lcnt; if (c > CAP) c = CAP;
        lcnt = c;
        lbase = atomicAdd(&gcount[b], c);
    }
    __syncthreads();
    u32 c = lcnt, base = lbase;
    for (u32 i = threadIdx.x; i < c; i += blockDim.x) {
        u32 p = base + i;
        if (p < CAP) gbuf[(size_t)b * CAP + p] = buf[i];
    }
}

// ---------------- sort (bitonic, desc) + decode top-K ----------------
__global__ __launch_bounds__(1024) void sort_decode(
    const u64* __restrict__ gbuf, const u32* __restrict__ gcount,
    const float* __restrict__ rois, const float* __restrict__ reg,
    float* __restrict__ tbox, float* __restrict__ tobox,
    float* __restrict__ tscore, float* __restrict__ tcls, u32* __restrict__ tvalid) {
    __shared__ u64 keys[CAP];
    int b = blockIdx.x;
    u32 cnt = gcount[b]; if (cnt > CAP) cnt = CAP;
    for (int i = threadIdx.x; i < CAP; i += blockDim.x)
        keys[i] = (i < (int)cnt) ? gbuf[(size_t)b * CAP + i] : 0ull;
    __syncthreads();
    for (int k = 2; k <= CAP; k <<= 1) {
        for (int j = k >> 1; j > 0; j >>= 1) {
            for (int i = threadIdx.x; i < CAP; i += blockDim.x) {
                int ixj = i ^ j;
                if (ixj > i) {
                    u64 a = keys[i], c = keys[ixj];
                    bool desc = ((i & k) == 0);
                    if ((a < c) == desc) { keys[i] = c; keys[ixj] = a; }
                }
            }
            __syncthreads();
        }
    }
    for (int kk = threadIdx.x; kk < KK; kk += blockDim.x) {
        u64 key = keys[kk];
        float score, cf, box0, box1, box2, box3;
        u32 vld;
        if (kk < (int)cnt) {
            u32 m = (u32)(key >> 32);
            u32 idx = (u32)MAXIDX - (u32)(key & 0xFFFFFFFFu);
            score = unmapf(m);
            vld = (score > SCORE_THR) ? 1u : 0u;
            int n = idx / CC, c = idx % CC;
            cf = (float)(c + 1);
            const float* r = rois + ((size_t)b * NN + n) * 4;
            const float* d = reg  + ((size_t)b * NN + n) * 4;
            float x1 = r[0], y1 = r[1], x2 = r[2], y2 = r[3];
            float w = x2 - x1, h = y2 - y1;
            float cx = x1 + 0.5f * w, cy = y1 + 0.5f * h;
            float dx = d[0], dy = d[1];
            float dw = fminf(fmaxf(d[2], -MAX_RATIO), MAX_RATIO);
            float dh = fminf(fmaxf(d[3], -MAX_RATIO), MAX_RATIO);
            float pw = w * expf(dw), ph = h * expf(dh);
            float pcx = cx + dx * w, pcy = cy + dy * h;
            box0 = pcx - 0.5f * pw; box1 = pcy - 0.5f * ph;
            box2 = pcx + 0.5f * pw; box3 = pcy + 0.5f * ph;
        } else {
            score = -1.0f; cf = 0.0f; vld = 0u; box0 = box1 = box2 = box3 = 0.0f;
        }
        size_t o = (size_t)b * KK + kk;
        tscore[o] = score; tcls[o] = cf; tvalid[o] = vld;
        float off = cf * CLS_OFF;
        tbox[o*4+0] = box0; tbox[o*4+1] = box1; tbox[o*4+2] = box2; tbox[o*4+3] = box3;
        tobox[o*4+0] = box0 + off; tobox[o*4+1] = box1 + off;
        tobox[o*4+2] = box2 + off; tobox[o*4+3] = box3 + off;
    }
}

// ---------------- IoU > thr bitmask, TRANSPOSED layout: maskT[b][w][i] ----------------
__global__ void iou_mask(const float* __restrict__ obox, u64* __restrict__ maskT) {
    __shared__ float jb[64][4];
    int b = blockIdx.z, ib = blockIdx.x, jbk = blockIdx.y;
    int t = threadIdx.x;
    int j0 = jbk * 64;
    int jg = j0 + t;
    if (jg < KK) {
        const float* p = obox + ((size_t)b * KK + jg) * 4;
        jb[t][0] = p[0]; jb[t][1] = p[1]; jb[t][2] = p[2]; jb[t][3] = p[3];
    } else {
        jb[t][0] = 0; jb[t][1] = 0; jb[t][2] = 0; jb[t][3] = 0;
    }
    __syncthreads();
    int i = ib * 64 + t;
    if (i >= KK) return;
    const float* p = obox + ((size_t)b * KK + i) * 4;
    float x1 = p[0], y1 = p[1], x2 = p[2], y2 = p[3];
    float ai = (x2 - x1) * (y2 - y1);
    u64 bits = 0;
    int jmax = min(64, KK - j0);
    for (int jj = 0; jj < jmax; ++jj) {
        float bx1 = jb[jj][0], by1 = jb[jj][1], bx2 = jb[jj][2], by2 = jb[jj][3];
        float aj = (bx2 - bx1) * (by2 - by1);
        float iw = fmaxf(fminf(x2, bx2) - fmaxf(x1, bx1), 0.0f);
        float ih = fmaxf(fminf(y2, by2) - fmaxf(y1, by1), 0.0f);
        float inter = iw * ih;
        float iou = inter / (ai + aj - inter + 1e-9f);
        if (iou > NMS_THR) bits |= (1ull << jj);
    }
    maskT[((size_t)b * NW + jbk) * KK + i] = bits;
}

// ---------------- blocked ballot fixed-point NMS + output ----------------
__global__ __launch_bounds__(256) void nms_scan(
    const u64* __restrict__ maskT, const u32* __restrict__ tvalid,
    const float* __restrict__ tbox, const float* __restrict__ tscore,
    const float* __restrict__ tcls, float* __restrict__ out) {
    __shared__ u64 skept[NW];
    int b = blockIdx.x;
    if (threadIdx.x < 64) {
        int lane = threadIdx.x;
        const u64* mT = maskT + (size_t)b * NW * KK;
        u64 keptW[NW];
        #pragma unroll
        for (int W = 0; W < NW; ++W) {
            int i = W * 64 + lane;
            bool inr = (i < KK);
            u64 row[NW];
            #pragma unroll
            for (int w = 0; w <= W; ++w)
                row[w] = inr ? mT[(size_t)w * KK + i] : 0ull;
            bool valid = inr && (tvalid[(size_t)b * KK + i] != 0u);
            u64 ext = 0;
            #pragma unroll
            for (int w = 0; w < W; ++w) ext |= keptW[w] & row[w];
            bool cand = valid && (ext == 0ull);
            u64 m_self = row[W] & ((1ull << lane) - 1ull);   // strictly-lower lanes
            u64 kept = __ballot(cand);
            while (true) {
                u64 k2 = __ballot(cand && ((kept & m_self) == 0ull));
                if (k2 == kept) break;
                kept = k2;
            }
            keptW[W] = kept;
            if (lane == 0) skept[W] = kept;
        }
    }
    __syncthreads();
    for (int kk = threadIdx.x; kk < KK; kk += blockDim.x) {
        size_t o = (size_t)b * KK + kk;
        float kf = (float)((skept[kk >> 6] >> (kk & 63)) & 1ull);
        float* op = out + o * 7;
        op[0] = tbox[o*4+0] * kf; op[1] = tbox[o*4+1] * kf;
        op[2] = tbox[o*4+2] * kf; op[3] = tbox[o*4+3] * kf;
        op[4] = tscore[o] * kf;   op[5] = tcls[o] * kf;   op[6] = kf;
    }
}

extern "C" void kernel_launch(void* const* d_in, const int* in_sizes, int n_in,
                              void* d_out, int out_size, void* d_ws, size_t ws_size,
                              hipStream_t stream) {
    const float* rois   = (const float*)d_in[0];   // (B,N,4)
    const float* scores = (const float*)d_in[1];   // (B*N,C,1,1) == (B, N*C)
    const float* reg    = (const float*)d_in[2];   // (B*N,4,1,1)
    float* out = (float*)d_out;

    char* ws = (char*)d_ws;
    u32* hist1  = (u32*)(ws + WS_HIST1);
    u32* hist2  = (u32*)(ws + WS_HIST2);
    u32* prefix = (u32*)(ws + WS_PREFIX);
    u32* kneed  = (u32*)(ws + WS_KNEED);
    u32* sstar  = (u32*)(ws + WS_SSTAR);
    u32* gcount = (u32*)(ws + WS_GCOUNT);
    u64* gbuf   = (u64*)(ws + WS_GBUF);
    float* tbox   = (float*)(ws + WS_TBOX);
    float* tobox  = (float*)(ws + WS_TOBOX);
    float* tscore = (float*)(ws + WS_TSCORE);
    float* tcls   = (float*)(ws + WS_TCLS);
    u32*   tvalid = (u32*)(ws + WS_TVALID);
    u64*   maskT  = (u64*)(ws + WS_MASK);

    hipMemsetAsync(d_ws, 0, WS_CTRL_END, stream);

    dim3 hgrid(SCAN_BLOCKS, BB);
    hist_pass<<<hgrid, 256, 0, stream>>>(scores, hist1, prefix, 0);
    select_pass<<<BB, 256, 0, stream>>>(hist1, prefix, kneed, sstar, 0);
    hist_pass<<<hgrid, 256, 0, stream>>>(scores, hist2, prefix, 1);
    select_pass<<<BB, 256, 0, stream>>>(hist2, prefix, kneed, sstar, 1);

    gather_pass<<<hgrid, 256, 0, stream>>>(scores, sstar, gbuf, gcount);

    sort_decode<<<BB, 1024, 0, stream>>>(gbuf, gcount, rois, reg,
                                         tbox, tobox, tscore, tcls, tvalid);

    iou_mask<<<dim3(16, 16, BB), 64, 0, stream>>>(tobox, maskT);

    nms_scan<<<BB, 256, 0, stream>>>(maskT, tvalid, tbox, tscore, tcls, out);
}

// Round 4
// 141.879 us; speedup vs baseline: 2.2892x; 1.0082x over previous
//
#include <hip/hip_runtime.h>
#include <stdint.h>

typedef unsigned int u32;
typedef unsigned long long u64;

#define BB 8
#define NN 8192
#define CC 80
#define KK 1000
#define NC (NN*CC)            // 655360
#define MAXIDX (NC-1)
#define NMS_THR 0.5f
#define SCORE_THR 0.05f
#define MAX_RATIO 4.135166556742356f
#define CLS_OFF 10000.0f
#define CAP 2048
#define NW 16                 // u64 words per mask row (ceil(1000/64))
#define SCAN_BLOCKS 128       // blocks per batch for scan kernels

// ---- workspace layout (bytes) ----
#define WS_HIST1   0          // 8*2048*4 = 65536
#define WS_HIST2   65536      // 65536
#define WS_GCOUNT  131072     // 32
#define WS_CTRL_END 131104    // zeroed by init_ws; = 16*8194
#define WS_GBUF    131104     // B*CAP*8 = 131072 -> ends 262176
#define WS_TBOX    262176     // B*K*4*4 = 128000
#define WS_TOBOX   390176     // 128000
#define WS_TSCORE  518176     // 32000
#define WS_TCLS    550176     // 32000
#define WS_TVALID  582176     // 32000
#define WS_MASK    614176     // transposed: B*NW*KK*8 = 1024000 -> ends 1638176

__device__ __forceinline__ u32 mapf(float f) {
    u32 u = __float_as_uint(f);
    return (u & 0x80000000u) ? ~u : (u | 0x80000000u);
}
__device__ __forceinline__ float unmapf(u32 m) {
    u32 u = (m & 0x80000000u) ? (m ^ 0x80000000u) : ~m;
    return __uint_as_float(u);
}

// ---------------- init: zero control region (replaces 40us rocclr fill) ----------------
__global__ __launch_bounds__(256) void init_ws(uint4* __restrict__ p) {
    int i = blockIdx.x * blockDim.x + threadIdx.x;
    if (i < (WS_CTRL_END / 16)) p[i] = make_uint4(0u, 0u, 0u, 0u);
}

// wave-aggregated LDS histogram add: one atomic per distinct bin per wave
__device__ __forceinline__ void agg_lds_add(u32* lh, u32 bin, bool active) {
    u64 unproc = __ballot(active);
    const int lane = threadIdx.x & 63;
    while (unproc) {
        int leader = __ffsll(unproc) - 1;
        u32 lbin = (u32)__shfl((int)bin, leader, 64);
        u64 match = __ballot(active && (bin == lbin));
        if (lane == leader) atomicAdd(&lh[lbin], (u32)__popcll(match));
        unproc &= ~match;
    }
}

// digit-select from a finalized 2048-bin histogram (descending): requires blockDim=256.
// bcast[0] = digit, bcast[1] = remaining need inside that digit.
__device__ __forceinline__ void sel_digit(const u32* __restrict__ h, u32 need,
                                          u32* suf, u32* bcast) {
    int t = threadIdx.x;
    u32 hv[8];
    u32 s = 0;
    #pragma unroll
    for (int q = 0; q < 8; ++q) { hv[q] = h[t * 8 + q]; s += hv[q]; }
    u32 grp = s;
    suf[t] = s;
    __syncthreads();
    #pragma unroll
    for (int off = 1; off < 256; off <<= 1) {
        u32 v = (t + off < 256) ? suf[t + off] : 0u;
        __syncthreads();
        suf[t] += v;
        __syncthreads();
    }
    u32 cumAbove = suf[t] - grp;
    if (cumAbove < need && suf[t] >= need) {   // unique boundary group
        u32 cum = cumAbove;
        int d = t * 8;
        for (int q = 7; q >= 0; --q) {
            if (cum + hv[q] >= need) { d = t * 8 + q; break; }
            cum += hv[q];
        }
        bcast[0] = (u32)d;
        bcast[1] = need - cum;
    }
    __syncthreads();
}

// ---------------- histogram pass (radix select, 2 passes of 11 bits) ----------------
template <int PASS>
__global__ __launch_bounds__(256) void hist_pass(
    const float* __restrict__ scores, const u32* __restrict__ hist_prev,
    u32* __restrict__ hist) {
    __shared__ u32 lh[2048];
    __shared__ u32 suf[256];
    __shared__ u32 bcast[2];
    int b = blockIdx.y;
    for (int i = threadIdx.x; i < 2048; i += blockDim.x) lh[i] = 0;
    __syncthreads();
    u32 pfx = 0;
    if (PASS == 1) {
        sel_digit(hist_prev + b * 2048, (u32)KK, suf, bcast);
        pfx = bcast[0];
    }
    const float4* sp = (const float4*)(scores + (size_t)b * NC);
    int nvec = NC / 4;
    for (int v = blockIdx.x * blockDim.x + threadIdx.x; v < nvec; v += gridDim.x * blockDim.x) {
        float4 s4 = sp[v];
        float ss[4] = {s4.x, s4.y, s4.z, s4.w};
        #pragma unroll
        for (int q = 0; q < 4; ++q) {
            float s = ss[q] > SCORE_THR ? ss[q] : -1.0f;
            u32 m = mapf(s);
            if (PASS == 0) {
                agg_lds_add(lh, m >> 21, true);
            } else {
                agg_lds_add(lh, (m >> 10) & 0x7FFu, (m >> 21) == pfx);
            }
        }
    }
    __syncthreads();
    for (int i = threadIdx.x; i < 2048; i += blockDim.x)
        if (lh[i]) atomicAdd(&hist[b * 2048 + i], lh[i]);
}

// ---------------- gather all >= s* (block-aggregated compaction) ----------------
__global__ __launch_bounds__(256) void gather_pass(
    const float* __restrict__ scores, const u32* __restrict__ hist1,
    const u32* __restrict__ hist2, u64* __restrict__ gbuf, u32* __restrict__ gcount) {
    __shared__ u64 buf[CAP];
    __shared__ u32 suf[256];
    __shared__ u32 bcast[2];
    __shared__ u32 lcnt, lbase;
    int b = blockIdx.y;
    if (threadIdx.x == 0) lcnt = 0;
    __syncthreads();
    sel_digit(hist1 + b * 2048, (u32)KK, suf, bcast);
    u32 d0 = bcast[0], rem = bcast[1];
    __syncthreads();
    sel_digit(hist2 + b * 2048, rem, suf, bcast);
    u32 thr = ((d0 << 11) | bcast[0]) << 10;
    const float4* sp = (const float4*)(scores + (size_t)b * NC);
    int nvec = NC / 4;
    for (int v = blockIdx.x * blockDim.x + threadIdx.x; v < nvec; v += gridDim.x * blockDim.x) {
        float4 s4 = sp[v];
        float ss[4] = {s4.x, s4.y, s4.z, s4.w};
        #pragma unroll
        for (int q = 0; q < 4; ++q) {
            float s = ss[q] > SCORE_THR ? ss[q] : -1.0f;
            u32 m = mapf(s);
            if (m >= thr) {
                u32 pos = atomicAdd(&lcnt, 1u);
                if (pos < CAP) {
                    u32 idx = (u32)(v * 4 + q);
                    buf[pos] = ((u64)m << 32) | (u64)(MAXIDX - idx);
                }
            }
        }
    }
    __syncthreads();
    if (threadIdx.x == 0) {
        u32 c = lcnt; if (c > CAP) c = CAP;
        lcnt = c;
        lbase = atomicAdd(&gcount[b], c);
    }
    __syncthreads();
    u32 c = lcnt, base = lbase;
    for (u32 i = threadIdx.x; i < c; i += blockDim.x) {
        u32 p = base + i;
        if (p < CAP) gbuf[(size_t)b * CAP + p] = buf[i];
    }
}

// ---------------- sort (bitonic, desc) + decode top-K ----------------
__global__ __launch_bounds__(1024) void sort_decode(
    const u64* __restrict__ gbuf, const u32* __restrict__ gcount,
    const float* __restrict__ rois, const float* __restrict__ reg,
    float* __restrict__ tbox, float* __restrict__ tobox,
    float* __restrict__ tscore, float* __restrict__ tcls, u32* __restrict__ tvalid) {
    __shared__ u64 keys[CAP];
    int b = blockIdx.x;
    u32 cnt = gcount[b]; if (cnt > CAP) cnt = CAP;
    for (int i = threadIdx.x; i < CAP; i += blockDim.x)
        keys[i] = (i < (int)cnt) ? gbuf[(size_t)b * CAP + i] : 0ull;
    __syncthreads();
    for (int k = 2; k <= CAP; k <<= 1) {
        for (int j = k >> 1; j > 0; j >>= 1) {
            for (int i = threadIdx.x; i < CAP; i += blockDim.x) {
                int ixj = i ^ j;
                if (ixj > i) {
                    u64 a = keys[i], c = keys[ixj];
                    bool desc = ((i & k) == 0);
                    if ((a < c) == desc) { keys[i] = c; keys[ixj] = a; }
                }
            }
            __syncthreads();
        }
    }
    for (int kk = threadIdx.x; kk < KK; kk += blockDim.x) {
        u64 key = keys[kk];
        float score, cf, box0, box1, box2, box3;
        u32 vld;
        if (kk < (int)cnt) {
            u32 m = (u32)(key >> 32);
            u32 idx = (u32)MAXIDX - (u32)(key & 0xFFFFFFFFu);
            score = unmapf(m);
            vld = (score > SCORE_THR) ? 1u : 0u;
            int n = idx / CC, c = idx % CC;
            cf = (float)(c + 1);
            const float* r = rois + ((size_t)b * NN + n) * 4;
            const float* d = reg  + ((size_t)b * NN + n) * 4;
            float x1 = r[0], y1 = r[1], x2 = r[2], y2 = r[3];
            float w = x2 - x1, h = y2 - y1;
            float cx = x1 + 0.5f * w, cy = y1 + 0.5f * h;
            float dx = d[0], dy = d[1];
            float dw = fminf(fmaxf(d[2], -MAX_RATIO), MAX_RATIO);
            float dh = fminf(fmaxf(d[3], -MAX_RATIO), MAX_RATIO);
            float pw = w * expf(dw), ph = h * expf(dh);
            float pcx = cx + dx * w, pcy = cy + dy * h;
            box0 = pcx - 0.5f * pw; box1 = pcy - 0.5f * ph;
            box2 = pcx + 0.5f * pw; box3 = pcy + 0.5f * ph;
        } else {
            score = -1.0f; cf = 0.0f; vld = 0u; box0 = box1 = box2 = box3 = 0.0f;
        }
        size_t o = (size_t)b * KK + kk;
        tscore[o] = score; tcls[o] = cf; tvalid[o] = vld;
        float off = cf * CLS_OFF;
        tbox[o*4+0] = box0; tbox[o*4+1] = box1; tbox[o*4+2] = box2; tbox[o*4+3] = box3;
        tobox[o*4+0] = box0 + off; tobox[o*4+1] = box1 + off;
        tobox[o*4+2] = box2 + off; tobox[o*4+3] = box3 + off;
    }
}

// ---------------- IoU > thr bitmask, TRANSPOSED layout: maskT[b][w][i] ----------------
__global__ void iou_mask(const float* __restrict__ obox, u64* __restrict__ maskT) {
    __shared__ float jb[64][4];
    int b = blockIdx.z, ib = blockIdx.x, jbk = blockIdx.y;
    int t = threadIdx.x;
    int j0 = jbk * 64;
    int jg = j0 + t;
    if (jg < KK) {
        const float* p = obox + ((size_t)b * KK + jg) * 4;
        jb[t][0] = p[0]; jb[t][1] = p[1]; jb[t][2] = p[2]; jb[t][3] = p[3];
    } else {
        jb[t][0] = 0; jb[t][1] = 0; jb[t][2] = 0; jb[t][3] = 0;
    }
    __syncthreads();
    int i = ib * 64 + t;
    if (i >= KK) return;
    const float* p = obox + ((size_t)b * KK + i) * 4;
    float x1 = p[0], y1 = p[1], x2 = p[2], y2 = p[3];
    float ai = (x2 - x1) * (y2 - y1);
    u64 bits = 0;
    int jmax = min(64, KK - j0);
    for (int jj = 0; jj < jmax; ++jj) {
        float bx1 = jb[jj][0], by1 = jb[jj][1], bx2 = jb[jj][2], by2 = jb[jj][3];
        float aj = (bx2 - bx1) * (by2 - by1);
        float iw = fmaxf(fminf(x2, bx2) - fmaxf(x1, bx1), 0.0f);
        float ih = fmaxf(fminf(y2, by2) - fmaxf(y1, by1), 0.0f);
        float inter = iw * ih;
        float iou = inter / (ai + aj - inter + 1e-9f);
        if (iou > NMS_THR) bits |= (1ull << jj);
    }
    maskT[((size_t)b * NW + jbk) * KK + i] = bits;
}

// ---------------- blocked ballot fixed-point NMS + output ----------------
__global__ __launch_bounds__(256) void nms_scan(
    const u64* __restrict__ maskT, const u32* __restrict__ tvalid,
    const float* __restrict__ tbox, const float* __restrict__ tscore,
    const float* __restrict__ tcls, float* __restrict__ out) {
    __shared__ u64 skept[NW];
    int b = blockIdx.x;
    if (threadIdx.x < 64) {
        int lane = threadIdx.x;
        const u64* mT = maskT + (size_t)b * NW * KK;
        u64 keptW[NW];
        #pragma unroll
        for (int W = 0; W < NW; ++W) {
            int i = W * 64 + lane;
            bool inr = (i < KK);
            u64 row[NW];
            #pragma unroll
            for (int w = 0; w <= W; ++w)
                row[w] = inr ? mT[(size_t)w * KK + i] : 0ull;
            bool valid = inr && (tvalid[(size_t)b * KK + i] != 0u);
            u64 ext = 0;
            #pragma unroll
            for (int w = 0; w < W; ++w) ext |= keptW[w] & row[w];
            bool cand = valid && (ext == 0ull);
            u64 m_self = row[W] & ((1ull << lane) - 1ull);   // strictly-lower lanes
            u64 kept = __ballot(cand);
            while (true) {
                u64 k2 = __ballot(cand && ((kept & m_self) == 0ull));
                if (k2 == kept) break;
                kept = k2;
            }
            keptW[W] = kept;
            if (lane == 0) skept[W] = kept;
        }
    }
    __syncthreads();
    for (int kk = threadIdx.x; kk < KK; kk += blockDim.x) {
        size_t o = (size_t)b * KK + kk;
        float kf = (float)((skept[kk >> 6] >> (kk & 63)) & 1ull);
        float* op = out + o * 7;
        op[0] = tbox[o*4+0] * kf; op[1] = tbox[o*4+1] * kf;
        op[2] = tbox[o*4+2] * kf; op[3] = tbox[o*4+3] * kf;
        op[4] = tscore[o] * kf;   op[5] = tcls[o] * kf;   op[6] = kf;
    }
}

extern "C" void kernel_launch(void* const* d_in, const int* in_sizes, int n_in,
                              void* d_out, int out_size, void* d_ws, size_t ws_size,
                              hipStream_t stream) {
    const float* rois   = (const float*)d_in[0];   // (B,N,4)
    const float* scores = (const float*)d_in[1];   // (B*N,C,1,1) == (B, N*C)
    const float* reg    = (const float*)d_in[2];   // (B*N,4,1,1)
    float* out = (float*)d_out;

    char* ws = (char*)d_ws;
    u32* hist1  = (u32*)(ws + WS_HIST1);
    u32* hist2  = (u32*)(ws + WS_HIST2);
    u32* gcount = (u32*)(ws + WS_GCOUNT);
    u64* gbuf   = (u64*)(ws + WS_GBUF);
    float* tbox   = (float*)(ws + WS_TBOX);
    float* tobox  = (float*)(ws + WS_TOBOX);
    float* tscore = (float*)(ws + WS_TSCORE);
    float* tcls   = (float*)(ws + WS_TCLS);
    u32*   tvalid = (u32*)(ws + WS_TVALID);
    u64*   maskT  = (u64*)(ws + WS_MASK);

    init_ws<<<(WS_CTRL_END / 16 + 255) / 256, 256, 0, stream>>>((uint4*)ws);

    dim3 hgrid(SCAN_BLOCKS, BB);
    hist_pass<0><<<hgrid, 256, 0, stream>>>(scores, nullptr, hist1);
    hist_pass<1><<<hgrid, 256, 0, stream>>>(scores, hist1, hist2);

    gather_pass<<<hgrid, 256, 0, stream>>>(scores, hist1, hist2, gbuf, gcount);

    sort_decode<<<BB, 1024, 0, stream>>>(gbuf, gcount, rois, reg,
                                         tbox, tobox, tscore, tcls, tvalid);

    iou_mask<<<dim3(16, 16, BB), 64, 0, stream>>>(tobox, maskT);

    nms_scan<<<BB, 256, 0, stream>>>(maskT, tvalid, tbox, tscore, tcls, out);
}

// Round 5
// 101.750 us; speedup vs baseline: 3.1920x; 1.3944x over previous
//
#include <hip/hip_runtime.h>
#include <stdint.h>

typedef unsigned int u32;
typedef unsigned long long u64;

#define BB 8
#define NN 8192
#define CC 80
#define KK 1000
#define NC (NN*CC)            // 655360
#define MAXIDX (NC-1)
#define NMS_THR 0.5f
#define SCORE_THR 0.05f
#define MAX_RATIO 4.135166556742356f
#define CLS_OFF 10000.0f
#define CAP 2048
#define NW 16                 // u64 words per mask row (ceil(1000/64))
#define SCAN_BLOCKS 128       // blocks per batch for scan kernels

// ---- workspace layout (bytes) ----
#define WS_HIST1   0          // 8*2048*4 = 65536
#define WS_HIST2   65536      // 65536
#define WS_GCOUNT  131072     // 32
#define WS_CTRL_END 131104    // zeroed by init_ws; = 16*8194
#define WS_GBUF    131104     // B*CAP*8 = 131072 -> ends 262176
#define WS_TBOX    262176     // B*K*4*4 = 128000
#define WS_TOBOX   390176     // 128000
#define WS_TSCORE  518176     // 32000
#define WS_TCLS    550176     // 32000
#define WS_TVALID  582176     // 32000
#define WS_MASK    614176     // transposed: B*NW*KK*8 = 1024000 -> ends 1638176

__device__ __forceinline__ u32 mapf(float f) {
    u32 u = __float_as_uint(f);
    return (u & 0x80000000u) ? ~u : (u | 0x80000000u);
}
__device__ __forceinline__ float unmapf(u32 m) {
    u32 u = (m & 0x80000000u) ? (m ^ 0x80000000u) : ~m;
    return __uint_as_float(u);
}

// ---------------- init: zero control region ----------------
__global__ __launch_bounds__(256) void init_ws(uint4* __restrict__ p) {
    int i = blockIdx.x * blockDim.x + threadIdx.x;
    if (i < (WS_CTRL_END / 16)) p[i] = make_uint4(0u, 0u, 0u, 0u);
}

// digit-select from a finalized 2048-bin histogram (descending): requires blockDim=256.
// bcast[0] = digit, bcast[1] = remaining need inside that digit.
__device__ __forceinline__ void sel_digit(const u32* __restrict__ h, u32 need,
                                          u32* suf, u32* bcast) {
    int t = threadIdx.x;
    u32 hv[8];
    u32 s = 0;
    #pragma unroll
    for (int q = 0; q < 8; ++q) { hv[q] = h[t * 8 + q]; s += hv[q]; }
    u32 grp = s;
    suf[t] = s;
    __syncthreads();
    #pragma unroll
    for (int off = 1; off < 256; off <<= 1) {
        u32 v = (t + off < 256) ? suf[t + off] : 0u;
        __syncthreads();
        suf[t] += v;
        __syncthreads();
    }
    u32 cumAbove = suf[t] - grp;
    if (cumAbove < need && suf[t] >= need) {   // unique boundary group
        u32 cum = cumAbove;
        int d = t * 8;
        for (int q = 7; q >= 0; --q) {
            if (cum + hv[q] >= need) { d = t * 8 + q; break; }
            cum += hv[q];
        }
        bcast[0] = (u32)d;
        bcast[1] = need - cum;
    }
    __syncthreads();
}

// ---------------- histogram pass (radix select, 2 passes of 11 bits) ----------------
template <int PASS>
__global__ __launch_bounds__(256) void hist_pass(
    const float* __restrict__ scores, const u32* __restrict__ hist_prev,
    u32* __restrict__ hist) {
    __shared__ u32 lh[2048];
    __shared__ u32 suf[256];
    __shared__ u32 bcast[2];
    int b = blockIdx.y;
    for (int i = threadIdx.x; i < 2048; i += blockDim.x) lh[i] = 0;
    __syncthreads();
    u32 pfx = 0;
    if (PASS == 1) {
        sel_digit(hist_prev + b * 2048, (u32)KK, suf, bcast);
        pfx = bcast[0];
    }
    const float4* sp = (const float4*)(scores + (size_t)b * NC);
    int nvec = NC / 4;
    for (int v = blockIdx.x * blockDim.x + threadIdx.x; v < nvec; v += gridDim.x * blockDim.x) {
        float4 s4 = sp[v];
        float ss[4] = {s4.x, s4.y, s4.z, s4.w};
        #pragma unroll
        for (int q = 0; q < 4; ++q) {
            float s = ss[q] > SCORE_THR ? ss[q] : -1.0f;
            u32 m = mapf(s);
            if (PASS == 0) {
                atomicAdd(&lh[m >> 21], 1u);
            } else {
                if ((m >> 21) == pfx) atomicAdd(&lh[(m >> 10) & 0x7FFu], 1u);
            }
        }
    }
    __syncthreads();
    for (int i = threadIdx.x; i < 2048; i += blockDim.x)
        if (lh[i]) atomicAdd(&hist[b * 2048 + i], lh[i]);
}

// ---------------- gather all >= s* (block-aggregated compaction) ----------------
__global__ __launch_bounds__(256) void gather_pass(
    const float* __restrict__ scores, const u32* __restrict__ hist1,
    const u32* __restrict__ hist2, u64* __restrict__ gbuf, u32* __restrict__ gcount) {
    __shared__ u64 buf[CAP];
    __shared__ u32 suf[256];
    __shared__ u32 bcast[2];
    __shared__ u32 lcnt, lbase;
    int b = blockIdx.y;
    if (threadIdx.x == 0) lcnt = 0;
    __syncthreads();
    sel_digit(hist1 + b * 2048, (u32)KK, suf, bcast);
    u32 d0 = bcast[0], rem = bcast[1];
    __syncthreads();
    sel_digit(hist2 + b * 2048, rem, suf, bcast);
    u32 thr = ((d0 << 11) | bcast[0]) << 10;
    const float4* sp = (const float4*)(scores + (size_t)b * NC);
    int nvec = NC / 4;
    for (int v = blockIdx.x * blockDim.x + threadIdx.x; v < nvec; v += gridDim.x * blockDim.x) {
        float4 s4 = sp[v];
        float ss[4] = {s4.x, s4.y, s4.z, s4.w};
        #pragma unroll
        for (int q = 0; q < 4; ++q) {
            float s = ss[q] > SCORE_THR ? ss[q] : -1.0f;
            u32 m = mapf(s);
            if (m >= thr) {
                u32 pos = atomicAdd(&lcnt, 1u);
                if (pos < CAP) {
                    u32 idx = (u32)(v * 4 + q);
                    buf[pos] = ((u64)m << 32) | (u64)(MAXIDX - idx);
                }
            }
        }
    }
    __syncthreads();
    if (threadIdx.x == 0) {
        u32 c = lcnt; if (c > CAP) c = CAP;
        lcnt = c;
        lbase = atomicAdd(&gcount[b], c);
    }
    __syncthreads();
    u32 c = lcnt, base = lbase;
    for (u32 i = threadIdx.x; i < c; i += blockDim.x) {
        u32 p = base + i;
        if (p < CAP) gbuf[(size_t)b * CAP + p] = buf[i];
    }
}

// ---------------- sort (bitonic, desc) + decode top-K ----------------
__global__ __launch_bounds__(1024) void sort_decode(
    const u64* __restrict__ gbuf, const u32* __restrict__ gcount,
    const float* __restrict__ rois, const float* __restrict__ reg,
    float* __restrict__ tbox, float* __restrict__ tobox,
    float* __restrict__ tscore, float* __restrict__ tcls, u32* __restrict__ tvalid) {
    __shared__ u64 keys[CAP];
    int b = blockIdx.x;
    u32 cnt = gcount[b]; if (cnt > CAP) cnt = CAP;
    for (int i = threadIdx.x; i < CAP; i += blockDim.x)
        keys[i] = (i < (int)cnt) ? gbuf[(size_t)b * CAP + i] : 0ull;
    __syncthreads();
    for (int k = 2; k <= CAP; k <<= 1) {
        for (int j = k >> 1; j > 0; j >>= 1) {
            for (int i = threadIdx.x; i < CAP; i += blockDim.x) {
                int ixj = i ^ j;
                if (ixj > i) {
                    u64 a = keys[i], c = keys[ixj];
                    bool desc = ((i & k) == 0);
                    if ((a < c) == desc) { keys[i] = c; keys[ixj] = a; }
                }
            }
            __syncthreads();
        }
    }
    for (int kk = threadIdx.x; kk < KK; kk += blockDim.x) {
        u64 key = keys[kk];
        float score, cf, box0, box1, box2, box3;
        u32 vld;
        if (kk < (int)cnt) {
            u32 m = (u32)(key >> 32);
            u32 idx = (u32)MAXIDX - (u32)(key & 0xFFFFFFFFu);
            score = unmapf(m);
            vld = (score > SCORE_THR) ? 1u : 0u;
            int n = idx / CC, c = idx % CC;
            cf = (float)(c + 1);
            const float* r = rois + ((size_t)b * NN + n) * 4;
            const float* d = reg  + ((size_t)b * NN + n) * 4;
            float x1 = r[0], y1 = r[1], x2 = r[2], y2 = r[3];
            float w = x2 - x1, h = y2 - y1;
            float cx = x1 + 0.5f * w, cy = y1 + 0.5f * h;
            float dx = d[0], dy = d[1];
            float dw = fminf(fmaxf(d[2], -MAX_RATIO), MAX_RATIO);
            float dh = fminf(fmaxf(d[3], -MAX_RATIO), MAX_RATIO);
            float pw = w * expf(dw), ph = h * expf(dh);
            float pcx = cx + dx * w, pcy = cy + dy * h;
            box0 = pcx - 0.5f * pw; box1 = pcy - 0.5f * ph;
            box2 = pcx + 0.5f * pw; box3 = pcy + 0.5f * ph;
        } else {
            score = -1.0f; cf = 0.0f; vld = 0u; box0 = box1 = box2 = box3 = 0.0f;
        }
        size_t o = (size_t)b * KK + kk;
        tscore[o] = score; tcls[o] = cf; tvalid[o] = vld;
        float off = cf * CLS_OFF;
        tbox[o*4+0] = box0; tbox[o*4+1] = box1; tbox[o*4+2] = box2; tbox[o*4+3] = box3;
        tobox[o*4+0] = box0 + off; tobox[o*4+1] = box1 + off;
        tobox[o*4+2] = box2 + off; tobox[o*4+3] = box3 + off;
    }
}

// ---------------- IoU > thr bitmask, lower-triangle only, maskT[b][w][i] ----------------
__global__ void iou_mask(const float* __restrict__ obox, u64* __restrict__ maskT) {
    __shared__ float jb[64][4];
    int b = blockIdx.z, ib = blockIdx.x, jbk = blockIdx.y;
    if (jbk > ib) return;           // nms_scan never reads these words
    int t = threadIdx.x;
    int j0 = jbk * 64;
    int jg = j0 + t;
    if (jg < KK) {
        const float* p = obox + ((size_t)b * KK + jg) * 4;
        jb[t][0] = p[0]; jb[t][1] = p[1]; jb[t][2] = p[2]; jb[t][3] = p[3];
    } else {
        jb[t][0] = 0; jb[t][1] = 0; jb[t][2] = 0; jb[t][3] = 0;
    }
    __syncthreads();
    int i = ib * 64 + t;
    if (i >= KK) return;
    const float* p = obox + ((size_t)b * KK + i) * 4;
    float x1 = p[0], y1 = p[1], x2 = p[2], y2 = p[3];
    float ai = (x2 - x1) * (y2 - y1);
    u64 bits = 0;
    int jmax = min(64, KK - j0);
    for (int jj = 0; jj < jmax; ++jj) {
        float bx1 = jb[jj][0], by1 = jb[jj][1], bx2 = jb[jj][2], by2 = jb[jj][3];
        float aj = (bx2 - bx1) * (by2 - by1);
        float iw = fmaxf(fminf(x2, bx2) - fmaxf(x1, bx1), 0.0f);
        float ih = fmaxf(fminf(y2, by2) - fmaxf(y1, by1), 0.0f);
        float inter = iw * ih;
        float iou = inter / (ai + aj - inter + 1e-9f);
        if (iou > NMS_THR) bits |= (1ull << jj);
    }
    maskT[((size_t)b * NW + jbk) * KK + i] = bits;
}

// ---------------- blocked ballot fixed-point NMS + output ----------------
__global__ __launch_bounds__(256) void nms_scan(
    const u64* __restrict__ maskT, const u32* __restrict__ tvalid,
    const float* __restrict__ tbox, const float* __restrict__ tscore,
    const float* __restrict__ tcls, float* __restrict__ out) {
    __shared__ u64 skept[NW];
    int b = blockIdx.x;
    if (threadIdx.x < 64) {
        int lane = threadIdx.x;
        const u64* mT = maskT + (size_t)b * NW * KK;
        u64 keptW[NW];
        #pragma unroll
        for (int W = 0; W < NW; ++W) {
            int i = W * 64 + lane;
            bool inr = (i < KK);
            u64 row[NW];
            #pragma unroll
            for (int w = 0; w <= W; ++w)
                row[w] = inr ? mT[(size_t)w * KK + i] : 0ull;
            bool valid = inr && (tvalid[(size_t)b * KK + i] != 0u);
            u64 ext = 0;
            #pragma unroll
            for (int w = 0; w < W; ++w) ext |= keptW[w] & row[w];
            bool cand = valid && (ext == 0ull);
            u64 m_self = row[W] & ((1ull << lane) - 1ull);   // strictly-lower lanes
            u64 kept = __ballot(cand);
            while (true) {
                u64 k2 = __ballot(cand && ((kept & m_self) == 0ull));
                if (k2 == kept) break;
                kept = k2;
            }
            keptW[W] = kept;
            if (lane == 0) skept[W] = kept;
        }
    }
    __syncthreads();
    for (int kk = threadIdx.x; kk < KK; kk += blockDim.x) {
        size_t o = (size_t)b * KK + kk;
        float kf = (float)((skept[kk >> 6] >> (kk & 63)) & 1ull);
        float* op = out + o * 7;
        op[0] = tbox[o*4+0] * kf; op[1] = tbox[o*4+1] * kf;
        op[2] = tbox[o*4+2] * kf; op[3] = tbox[o*4+3] * kf;
        op[4] = tscore[o] * kf;   op[5] = tcls[o] * kf;   op[6] = kf;
    }
}

extern "C" void kernel_launch(void* const* d_in, const int* in_sizes, int n_in,
                              void* d_out, int out_size, void* d_ws, size_t ws_size,
                              hipStream_t stream) {
    const float* rois   = (const float*)d_in[0];   // (B,N,4)
    const float* scores = (const float*)d_in[1];   // (B*N,C,1,1) == (B, N*C)
    const float* reg    = (const float*)d_in[2];   // (B*N,4,1,1)
    float* out = (float*)d_out;

    char* ws = (char*)d_ws;
    u32* hist1  = (u32*)(ws + WS_HIST1);
    u32* hist2  = (u32*)(ws + WS_HIST2);
    u32* gcount = (u32*)(ws + WS_GCOUNT);
    u64* gbuf   = (u64*)(ws + WS_GBUF);
    float* tbox   = (float*)(ws + WS_TBOX);
    float* tobox  = (float*)(ws + WS_TOBOX);
    float* tscore = (float*)(ws + WS_TSCORE);
    float* tcls   = (float*)(ws + WS_TCLS);
    u32*   tvalid = (u32*)(ws + WS_TVALID);
    u64*   maskT  = (u64*)(ws + WS_MASK);

    init_ws<<<(WS_CTRL_END / 16 + 255) / 256, 256, 0, stream>>>((uint4*)ws);

    dim3 hgrid(SCAN_BLOCKS, BB);
    hist_pass<0><<<hgrid, 256, 0, stream>>>(scores, nullptr, hist1);
    hist_pass<1><<<hgrid, 256, 0, stream>>>(scores, hist1, hist2);

    gather_pass<<<hgrid, 256, 0, stream>>>(scores, hist1, hist2, gbuf, gcount);

    sort_decode<<<BB, 1024, 0, stream>>>(gbuf, gcount, rois, reg,
                                         tbox, tobox, tscore, tcls, tvalid);

    iou_mask<<<dim3(16, 16, BB), 64, 0, stream>>>(tobox, maskT);

    nms_scan<<<BB, 256, 0, stream>>>(maskT, tvalid, tbox, tscore, tcls, out);
}